// Round 4
// baseline (291.990 us; speedup 1.0000x reference)
//
#include <hip/hip_runtime.h>

// MessagePassing: out = segment_sum(x[col], row, N)
// x: [N=100000, 32] fp32; edge_index: [2, E=1600000] int32 (row; col)
//
// CSR two-phase formulation (no fp32 atomics):
//   1. k_count      : counts[r]++ per edge            (int atomics)
//   2. k_reduce/k_scan_bsums/k_scan_final : exclusive scan -> offs, cursor
//   3. k_fill       : csr_col[cursor[r]++] = col      (int atomics)
//   4. k_gather     : out[i] = sum_j x[csr_col[offs[i]+j]]  (pure gather-sum,
//                     4-way unrolled for memory-level parallelism)
// Fallback to direct atomic scatter if ws_size is insufficient.

#define FEAT  32
#define QUADS 8          // FEAT/4
#define BLK   256

// ---------------- fallback: atomic scatter ----------------
__global__ __launch_bounds__(256) void mp_scatter_add(
    const float* __restrict__ x, const int* __restrict__ row,
    const int* __restrict__ col, float* __restrict__ out, int E)
{
    int tid = blockIdx.x * blockDim.x + threadIdx.x;
    int e = tid >> 3, q = tid & 7;
    if (e >= E) return;
    int r = row[e], c = col[e];
    float4 v = reinterpret_cast<const float4*>(x)[(size_t)c * QUADS + q];
    float* o = out + (size_t)r * FEAT + q * 4;
    atomicAdd(o + 0, v.x); atomicAdd(o + 1, v.y);
    atomicAdd(o + 2, v.z); atomicAdd(o + 3, v.w);
}

// ---------------- CSR pipeline ----------------
__global__ __launch_bounds__(256) void k_count(
    const int* __restrict__ row, int* __restrict__ counts, int E)
{
    int e = blockIdx.x * blockDim.x + threadIdx.x;
    if (e < E) atomicAdd(&counts[row[e]], 1);
}

__global__ __launch_bounds__(256) void k_reduce(
    const int* __restrict__ counts, int* __restrict__ bsum, int N)
{
    __shared__ int sm[BLK];
    int i = blockIdx.x * BLK + threadIdx.x;
    sm[threadIdx.x] = (i < N) ? counts[i] : 0;
    __syncthreads();
    for (int off = BLK / 2; off > 0; off >>= 1) {
        if (threadIdx.x < off) sm[threadIdx.x] += sm[threadIdx.x + off];
        __syncthreads();
    }
    if (threadIdx.x == 0) bsum[blockIdx.x] = sm[0];
}

__global__ __launch_bounds__(512) void k_scan_bsums(int* bsum, int nblk)
{
    // single block; exclusive scan in place (requires nblk <= 512)
    __shared__ int sm[512];
    int t = threadIdx.x;
    int v = (t < nblk) ? bsum[t] : 0;
    sm[t] = v;
    __syncthreads();
    for (int off = 1; off < 512; off <<= 1) {
        int u = (t >= off) ? sm[t - off] : 0;
        __syncthreads();
        sm[t] += u;
        __syncthreads();
    }
    if (t < nblk) bsum[t] = sm[t] - v;   // inclusive -> exclusive
}

__global__ __launch_bounds__(256) void k_scan_final(
    const int* __restrict__ counts, const int* __restrict__ bsum,
    int* __restrict__ offs, int* __restrict__ cursor, int N)
{
    __shared__ int sm[BLK];
    int t = threadIdx.x;
    int i = blockIdx.x * BLK + t;
    int v = (i < N) ? counts[i] : 0;
    sm[t] = v;
    __syncthreads();
    for (int off = 1; off < BLK; off <<= 1) {
        int u = (t >= off) ? sm[t - off] : 0;
        __syncthreads();
        sm[t] += u;
        __syncthreads();
    }
    if (i < N) {
        int o = bsum[blockIdx.x] + sm[t] - v;   // block base + exclusive-in-block
        offs[i]   = o;
        cursor[i] = o;
    }
}

__global__ __launch_bounds__(256) void k_fill(
    const int* __restrict__ row, const int* __restrict__ col,
    int* __restrict__ cursor, int* __restrict__ csr_col, int E)
{
    int e = blockIdx.x * blockDim.x + threadIdx.x;
    if (e < E) {
        int p = atomicAdd(&cursor[row[e]], 1);
        csr_col[p] = col[e];
    }
}

__global__ __launch_bounds__(256) void k_gather(
    const float* __restrict__ x, const int* __restrict__ offs,
    const int* __restrict__ counts, const int* __restrict__ csr_col,
    float* __restrict__ out, int N)
{
    int tid = blockIdx.x * blockDim.x + threadIdx.x;
    int i = tid >> 3, q = tid & 7;
    if (i >= N) return;
    int deg = counts[i];
    const int* cl = csr_col + offs[i];
    const float4* x4 = reinterpret_cast<const float4*>(x);

    // 4-way unrolled, independent accumulators: 4 index loads + 4 float4
    // gathers in flight per iteration (gather is cache-latency-bound).
    float4 a0 = make_float4(0.f, 0.f, 0.f, 0.f);
    float4 a1 = make_float4(0.f, 0.f, 0.f, 0.f);
    float4 a2 = make_float4(0.f, 0.f, 0.f, 0.f);
    float4 a3 = make_float4(0.f, 0.f, 0.f, 0.f);
    int j = 0;
    for (; j + 4 <= deg; j += 4) {
        int c0 = cl[j], c1 = cl[j + 1], c2 = cl[j + 2], c3 = cl[j + 3];
        float4 v0 = x4[(size_t)c0 * QUADS + q];
        float4 v1 = x4[(size_t)c1 * QUADS + q];
        float4 v2 = x4[(size_t)c2 * QUADS + q];
        float4 v3 = x4[(size_t)c3 * QUADS + q];
        a0.x += v0.x; a0.y += v0.y; a0.z += v0.z; a0.w += v0.w;
        a1.x += v1.x; a1.y += v1.y; a1.z += v1.z; a1.w += v1.w;
        a2.x += v2.x; a2.y += v2.y; a2.z += v2.z; a2.w += v2.w;
        a3.x += v3.x; a3.y += v3.y; a3.z += v3.z; a3.w += v3.w;
    }
    for (; j < deg; ++j) {
        int c0 = cl[j];
        float4 v0 = x4[(size_t)c0 * QUADS + q];
        a0.x += v0.x; a0.y += v0.y; a0.z += v0.z; a0.w += v0.w;
    }
    a0.x += a1.x + a2.x + a3.x;
    a0.y += a1.y + a2.y + a3.y;
    a0.z += a1.z + a2.z + a3.z;
    a0.w += a1.w + a2.w + a3.w;
    reinterpret_cast<float4*>(out)[(size_t)i * QUADS + q] = a0;
}

extern "C" void kernel_launch(void* const* d_in, const int* in_sizes, int n_in,
                              void* d_out, int out_size, void* d_ws, size_t ws_size,
                              hipStream_t stream) {
    const float* x   = (const float*)d_in[0];
    const int*   ei  = (const int*)d_in[1];
    float*       out = (float*)d_out;

    const int E = in_sizes[1] / 2;           // edge_index is [2, E]
    const int N = in_sizes[0] / FEAT;        // 100000
    const int* row = ei;
    const int* col = ei + E;

    const int nblk = (N + BLK - 1) / BLK;    // 391 for N=100000

    // workspace layout (ints): counts[N] | offs[N] | cursor[N] | bsum[nblk] | csr_col[E]
    int* counts  = (int*)d_ws;
    int* offs    = counts + N;
    int* cursor  = offs + N;
    int* bsum    = cursor + N;
    int* csr_col = bsum + nblk;
    size_t need = ((size_t)3 * N + nblk + E) * sizeof(int);

    if (ws_size >= need && nblk <= 512) {
        // ws is re-poisoned (0xAA) before every launch -> zero the histogram
        hipMemsetAsync(counts, 0, (size_t)N * sizeof(int), stream);
        k_count     <<<(E + BLK - 1) / BLK, BLK, 0, stream>>>(row, counts, E);
        k_reduce    <<<nblk, BLK, 0, stream>>>(counts, bsum, N);
        k_scan_bsums<<<1, 512, 0, stream>>>(bsum, nblk);
        k_scan_final<<<nblk, BLK, 0, stream>>>(counts, bsum, offs, cursor, N);
        k_fill      <<<(E + BLK - 1) / BLK, BLK, 0, stream>>>(row, col, cursor, csr_col, E);
        const int total = N * QUADS;
        k_gather    <<<(total + BLK - 1) / BLK, BLK, 0, stream>>>(x, offs, counts, csr_col, out, N);
    } else {
        // fallback: direct atomic scatter
        hipMemsetAsync(d_out, 0, (size_t)out_size * sizeof(float), stream);
        const int total = E * QUADS;
        mp_scatter_add<<<(total + BLK - 1) / BLK, BLK, 0, stream>>>(x, row, col, out, E);
    }
}